// Round 1
// baseline (162.433 us; speedup 1.0000x reference)
//
#include <hip/hip_runtime.h>
#include <hip/hip_bf16.h>

#define BB 4
#define CC 128
#define TWOC 256
#define NN 4096
#define KK 16
#define COUT 256
#define NODES (BB*NN)

typedef __attribute__((ext_vector_type(8))) short short8;
typedef __attribute__((ext_vector_type(4))) float f32x4;

__device__ __forceinline__ short f2bs(float f) {
  union { __hip_bfloat16 h; short s; } u;
  u.h = __float2bfloat16(f);
  return u.s;
}
__device__ __forceinline__ float bs2f(unsigned short s) {
  union { unsigned int u; float f; } v;
  v.u = ((unsigned int)s) << 16;
  return v.f;
}

// K0: transpose x [B][C][N] f32 -> featbf [B][N][C] bf16
__global__ void __launch_bounds__(256) k0_transpose(const float* __restrict__ x,
                                                    unsigned short* __restrict__ featbf) {
  __shared__ float tile[64][129];
  int b = blockIdx.x >> 6;
  int n0 = (blockIdx.x & 63) << 6;
  int t = threadIdx.x;
#pragma unroll
  for (int i = 0; i < 32; ++i) {
    int flat = t + i * 256;       // 0..8191
    int c = flat >> 6;            // 0..127
    int nl = flat & 63;
    tile[nl][c] = x[((size_t)(b * CC + c) * NN) + n0 + nl];
  }
  __syncthreads();
#pragma unroll
  for (int i = 0; i < 8; ++i) {
    int e = t + i * 256;          // 0..2047
    int c4 = (e & 31) << 2;
    int nl = e >> 5;
    ushort4 u;
    u.x = (unsigned short)f2bs(tile[nl][c4 + 0]);
    u.y = (unsigned short)f2bs(tile[nl][c4 + 1]);
    u.z = (unsigned short)f2bs(tile[nl][c4 + 2]);
    u.w = (unsigned short)f2bs(tile[nl][c4 + 3]);
    *(ushort4*)(featbf + ((size_t)(b * NN + n0 + nl) * CC + c4)) = u;
  }
}

// K1: per node gather -> h[16][256] (LDS, XOR-swizzled) -> MFMA vs register-resident w^T
//     -> relu -> per-(node,col) max/min to ws, per-col sum/sumsq atomics
__global__ void __launch_bounds__(256, 2) k1_main(
    const unsigned short* __restrict__ featbf,
    const float* __restrict__ w, const float* __restrict__ bias,
    const int* __restrict__ eidx,
    float* __restrict__ nmax, float* __restrict__ nmin,
    float* __restrict__ gsum, float* __restrict__ gsq)
{
  __shared__ short hsh[16 * 256];   // 8 KB
  char* hb = (char*)hsh;
  const int tid = threadIdx.x;
  const int wave = tid >> 6;
  const int lane = tid & 63;
  const int l15 = lane & 15;
  const int lhi = lane >> 4;
  const int colbase = wave * 64;

  // B fragments: B[k][col] = w[col][k]; lane holds k = t*32 + lhi*8 + j, col = colbase+ct*16+l15
  short8 bfrag[8][4];
#pragma unroll
  for (int t = 0; t < 8; ++t)
#pragma unroll
    for (int ct = 0; ct < 4; ++ct) {
      int col = colbase + ct * 16 + l15;
      int k0 = t * 32 + lhi * 8;
      const float* wr = w + (size_t)col * TWOC + k0;
      short8 f;
#pragma unroll
      for (int j = 0; j < 8; ++j) f[j] = f2bs(wr[j]);
      bfrag[t][ct] = f;
    }
  float biasv[4];
#pragma unroll
  for (int ct = 0; ct < 4; ++ct) biasv[ct] = bias[colbase + ct * 16 + l15];

  float cs[4] = {0.f, 0.f, 0.f, 0.f};
  float cq[4] = {0.f, 0.f, 0.f, 0.f};

  const int r  = tid >> 4;          // staging row 0..15
  const int c8 = (tid & 15) * 8;    // staging channel base
  const int swz = (r & 7) << 4;

  const int g0 = blockIdx.x * 32;
  for (int it = 0; it < 32; ++it) {
    const int g = g0 + it;
    const int b = g >> 12;          // N=4096
    const int n = g & (NN - 1);

    // ---- stage h ----
    const int eb = (b * NN + n) * KK + r;
    const int idx_j = eidx[eb];                          // edge_index[0]
    const int idx_i = eidx[(size_t)BB * NN * KK + eb];   // edge_index[1]
    uint4 fi = *(const uint4*)(featbf + (size_t)(b * NN + idx_i) * CC + c8);
    uint4 fj = *(const uint4*)(featbf + (size_t)(b * NN + idx_j) * CC + c8);
    *(uint4*)(hb + (((r * 256 + c8) * 2) ^ swz)) = fi;
    uint4 d;
    {
      unsigned int* pi = (unsigned int*)&fi;
      unsigned int* pj = (unsigned int*)&fj;
      unsigned int* pd = (unsigned int*)&d;
#pragma unroll
      for (int q = 0; q < 4; ++q) {
        float lo = bs2f((unsigned short)(pj[q] & 0xffff)) - bs2f((unsigned short)(pi[q] & 0xffff));
        float hi = bs2f((unsigned short)(pj[q] >> 16))    - bs2f((unsigned short)(pi[q] >> 16));
        pd[q] = ((unsigned int)(unsigned short)f2bs(lo)) |
                (((unsigned int)(unsigned short)f2bs(hi)) << 16);
      }
    }
    *(uint4*)(hb + (((r * 256 + 128 + c8) * 2) ^ swz)) = d;
    __syncthreads();

    // ---- A fragments: row = l15, k = t*32 + lhi*8 ----
    short8 a[8];
    const int aswz = (l15 & 7) << 4;
#pragma unroll
    for (int t = 0; t < 8; ++t)
      a[t] = *(short8*)(hb + (((l15 * 256 + t * 32 + lhi * 8) * 2) ^ aswz));

    f32x4 acc[4] = {};
#pragma unroll
    for (int ct = 0; ct < 4; ++ct)
#pragma unroll
      for (int t = 0; t < 8; ++t)
        acc[ct] = __builtin_amdgcn_mfma_f32_16x16x32_bf16(a[t], bfrag[t][ct], acc[ct], 0, 0, 0);

    // ---- epilogue: relu, K-reduce max/min, accumulate stats ----
#pragma unroll
    for (int ct = 0; ct < 4; ++ct) {
      float vmax = -1e30f, vmin = 1e30f, vs = 0.f, vq = 0.f;
#pragma unroll
      for (int i = 0; i < 4; ++i) {
        float v = acc[ct][i] + biasv[ct];
        v = fmaxf(v, 0.f);
        vmax = fmaxf(vmax, v);
        vmin = fminf(vmin, v);
        vs += v;
        vq += v * v;
      }
      cs[ct] += vs;
      cq[ct] += vq;
      vmax = fmaxf(vmax, __shfl_xor(vmax, 16));
      vmax = fmaxf(vmax, __shfl_xor(vmax, 32));
      vmin = fminf(vmin, __shfl_xor(vmin, 16));
      vmin = fminf(vmin, __shfl_xor(vmin, 32));
      if (lane < 16) {
        int col = colbase + ct * 16 + l15;
        nmax[(size_t)g * COUT + col] = vmax;
        nmin[(size_t)g * COUT + col] = vmin;
      }
    }
    __syncthreads();   // before next iteration overwrites hsh
  }

  // per-block stats -> global atomics (one add per col per block)
#pragma unroll
  for (int ct = 0; ct < 4; ++ct) {
    float s = cs[ct], q = cq[ct];
    s += __shfl_xor(s, 16);  s += __shfl_xor(s, 32);
    q += __shfl_xor(q, 16);  q += __shfl_xor(q, 32);
    if (lane < 16) {
      int col = colbase + ct * 16 + l15;
      atomicAdd(&gsum[col], s);
      atomicAdd(&gsq[col], q);
    }
  }
}

// K2a: finalize BN affine
__global__ void __launch_bounds__(256) k2a_scale(const float* __restrict__ gsum,
                                                 const float* __restrict__ gsq,
                                                 const float* __restrict__ gamma,
                                                 const float* __restrict__ beta,
                                                 float* __restrict__ scale,
                                                 float* __restrict__ shiftv) {
  int o = threadIdx.x;
  const float inv = 1.0f / (float)((size_t)BB * NN * KK);
  float mean = gsum[o] * inv;
  float var = gsq[o] * inv - mean * mean;
  float sc = gamma[o] * rsqrtf(var + 1e-5f);
  scale[o] = sc;
  shiftv[o] = beta[o] - mean * sc;
}

// K2b: out[b][o][n] = scale>=0 ? scale*nmax+shift : scale*nmin+shift  (LDS transpose)
__global__ void __launch_bounds__(256) k2b_out(const float* __restrict__ nmax,
                                               const float* __restrict__ nmin,
                                               const float* __restrict__ scale,
                                               const float* __restrict__ shiftv,
                                               float* __restrict__ out) {
  __shared__ float tile[COUT][33];
  int b = blockIdx.x >> 7;            // N/32 = 128 tiles per batch
  int n0 = (blockIdx.x & 127) << 5;
  int t = threadIdx.x;
  float sc = scale[t], sh = shiftv[t];
#pragma unroll
  for (int rr = 0; rr < 32; ++rr) {
    size_t g = (size_t)(b * NN + n0 + rr) * COUT + t;
    float mx = nmax[g], mn = nmin[g];
    tile[t][rr] = (sc >= 0.f ? mx : mn) * sc + sh;
  }
  __syncthreads();
#pragma unroll
  for (int i = 0; i < 32; ++i) {
    int o = i * 8 + (t >> 5);
    int nl = t & 31;
    out[((size_t)(b * COUT + o) * NN) + n0 + nl] = tile[o][nl];
  }
}

extern "C" void kernel_launch(void* const* d_in, const int* in_sizes, int n_in,
                              void* d_out, int out_size, void* d_ws, size_t ws_size,
                              hipStream_t stream) {
  const float* x     = (const float*)d_in[0];
  const float* w     = (const float*)d_in[1];
  const float* bias  = (const float*)d_in[2];
  const float* gamma = (const float*)d_in[3];
  const float* beta  = (const float*)d_in[4];
  const int*   eidx  = (const int*)d_in[5];

  // ws layout (needs ~38 MB):
  char* ws = (char*)d_ws;
  unsigned short* featbf = (unsigned short*)(ws);            //  4,194,304 B
  float* nmax   = (float*)(ws + 4194304);                    // 16,777,216 B
  float* nmin   = (float*)(ws + 20971520);                   // 16,777,216 B
  float* gsum   = (float*)(ws + 37748736);                   //      1,024 B
  float* gsq    = (float*)(ws + 37749760);                   //      1,024 B
  float* scale  = (float*)(ws + 37750784);                   //      1,024 B
  float* shiftv = (float*)(ws + 37751808);                   //      1,024 B
  float* out = (float*)d_out;

  hipMemsetAsync(gsum, 0, 2048, stream);  // zeros gsum+gsq (adjacent)
  k0_transpose<<<256, 256, 0, stream>>>(x, featbf);
  k1_main<<<512, 256, 0, stream>>>(featbf, w, bias, eidx, nmax, nmin, gsum, gsq);
  k2a_scale<<<1, 256, 0, stream>>>(gsum, gsq, gamma, beta, scale, shiftv);
  k2b_out<<<512, 256, 0, stream>>>(nmax, nmin, scale, shiftv, out);
}